// Round 1
// 677.527 us; speedup vs baseline: 1.0753x; 1.0753x over previous
//
#include <hip/hip_runtime.h>

#define B_DIM 256
#define H_DIM 4608
#define K_X   512
#define K_TOT 5120
#define NSTEP 160   // K_TOT / 32

typedef __attribute__((ext_vector_type(8))) short  short8;   // 8 x bf16
typedef __attribute__((ext_vector_type(4))) float  floatx4;  // MFMA C/D frag

// Raw barrier: lgkmcnt(0) drains ds_writes for cross-wave visibility, but no
// vmcnt(0) drain -> in-flight global prefetches survive the barrier (T3/T4).
#define BAR() do { \
  __builtin_amdgcn_sched_barrier(0); \
  asm volatile("s_waitcnt lgkmcnt(0)" ::: "memory"); \
  __builtin_amdgcn_s_barrier(); \
  __builtin_amdgcn_sched_barrier(0); \
} while (0)

static __device__ __forceinline__ unsigned pkbf(float a, float b){
  unsigned ua = (__float_as_uint(a) + 0x8000u) >> 16;
  unsigned ub = (__float_as_uint(b) + 0x8000u) & 0xFFFF0000u;
  return ua | ub;
}
static __device__ __forceinline__ float sigm(float v){ return 1.0f / (1.0f + __expf(-v)); }
static __device__ __forceinline__ float tanh_fast(float v){
  float ax = fabsf(v);
  float e  = __expf(-2.0f * ax);
  float t  = (1.0f - e) / (1.0f + e);
  return copysignf(t, v);
}

// ---------- kernel 0: pack [x | h0] -> bf16 A (256 x 5120), zero z ----------
__global__ __launch_bounds__(256) void conv_kernel(
    const float* __restrict__ x, const float* __restrict__ h0,
    unsigned short* __restrict__ Abf, float* __restrict__ z)
{
  const int t = threadIdx.x;
  if (blockIdx.x == 0) ((float4*)z)[t] = make_float4(0.f, 0.f, 0.f, 0.f); // 1024 floats
  const long e = ((long)blockIdx.x * 256 + t) * 8;     // element index, 8 per thread
  const int  b = (int)(e / K_TOT);
  const int  k = (int)(e - (long)b * K_TOT);
  const float* src = (k < K_X) ? (x + (long)b * K_X + k)
                               : (h0 + (long)b * H_DIM + (k - K_X));
  float4 v0 = *(const float4*)src;
  float4 v1 = *(const float4*)(src + 4);
  uint4 wv;
  wv.x = pkbf(v0.x, v0.y); wv.y = pkbf(v0.z, v0.w);
  wv.z = pkbf(v1.x, v1.y); wv.w = pkbf(v1.z, v1.w);
  *(uint4*)(Abf + e) = wv;
}

// ---------- kernel 1: gates GEMM + LSTM cell + z-partials ----------
// Block: 256 thr = 4 waves, tile M=256 x N=64 (4 gates x 16 j), K-step 32.
// A-frags: direct global loads from bf16 Abf (L2-resident, wave-private).
// B (W rows): fp32 -> regs (4-slot rotating prefetch, issue->write depth 3)
//             -> bf16 -> XOR-swizzled 2x4KB LDS double buffer.
__global__ __launch_bounds__(256, 2) void lstm_gates_kernel(
    const unsigned short* __restrict__ Abf,
    const float* __restrict__ x,
    const float* __restrict__ c0,
    const float* __restrict__ Wih, const float* __restrict__ Whh,
    const float* __restrict__ bih, const float* __restrict__ bhh,
    float* __restrict__ outH, float* __restrict__ outC,
    float* __restrict__ z)
{
  __shared__ __align__(16) unsigned short Bs[2][64 * 32];  // 2 x 4 KB, swizzled

  const int t    = threadIdx.x;
  const int j0   = blockIdx.x * 16;
  const int w    = t >> 6;
  const int l    = t & 63;
  const int q    = l >> 4;
  const int col  = l & 15;
  const int jj   = j0 + col;
  const int wrow = w * 64;

  // A-frag base: batch row (wrow+col [+mt*16]), k-chunk q*8
  const long aBase = (long)(wrow + col) * K_TOT + q * 8;

  // B staging: thread covers W row rB, fp32 chunk cB (8 floats)
  const int  rB   = t >> 2;
  const int  cB   = t & 3;
  const int  gate = rB >> 4;
  const int  jl   = rB & 15;
  const long wrowg = (long)gate * H_DIM + j0 + jl;
  const float* __restrict__ pWx = Wih + wrowg * K_X   + cB * 8;
  const float* __restrict__ pWh = Whh + wrowg * H_DIM + cB * 8;

  // LDS cell for (row r, chunk c) lives at byte r*64 + ((c ^ ((r>>1)&3))<<4):
  // spreads 16-row b128 column reads over 8 bank-slots (2-way = free).
  char* ldsBase = (char*)&Bs[0][0];
  const int bwByte = rB  * 64 + ((cB ^ ((rB  >> 1) & 3)) << 4);           // write
  const int brByte = col * 64 + ((q  ^ ((col >> 1) & 3)) << 4);           // read (+nt*1024)

  floatx4 acc[4][4];
  #pragma unroll
  for (int nt = 0; nt < 4; ++nt){
    float bsum = bih[nt * H_DIM + jj] + bhh[nt * H_DIM + jj];
    floatx4 v = {bsum, bsum, bsum, bsum};
    #pragma unroll
    for (int mt = 0; mt < 4; ++mt) acc[mt][nt] = v;
  }

  float4 pb[4][2];          // 4 rotating B prefetch slots (slot = tile & 3)
  short8 af0[4], af1[4];    // A-frag double buffer

  auto issueB = [&](int kt, int slot){
    const int ko = kt * 32;
    const float* p = (ko < K_X) ? (pWx + ko) : (pWh + (ko - K_X));
    pb[slot][0] = *(const float4*)p;
    pb[slot][1] = *(const float4*)(p + 4);
  };
  auto writeB = [&](int slot, int buf){
    uint4 wv;
    wv.x = pkbf(pb[slot][0].x, pb[slot][0].y);
    wv.y = pkbf(pb[slot][0].z, pb[slot][0].w);
    wv.z = pkbf(pb[slot][1].x, pb[slot][1].y);
    wv.w = pkbf(pb[slot][1].z, pb[slot][1].w);
    *(uint4*)(ldsBase + buf * 4096 + bwByte) = wv;
  };
  auto loadA = [&](int kt, short8* af){
    const unsigned short* p = Abf + (aBase + kt * 32);
    #pragma unroll
    for (int mt = 0; mt < 4; ++mt)
      af[mt] = *(const short8*)(p + (long)mt * (16 * K_TOT));
  };
  auto mfmaStep = [&](int buf, const short8* af){
    short8 bf[4];
    #pragma unroll
    for (int nt = 0; nt < 4; ++nt)
      bf[nt] = *(const short8*)(ldsBase + buf * 4096 + brByte + nt * 1024);
    #pragma unroll
    for (int mt = 0; mt < 4; ++mt)
      #pragma unroll
      for (int nt = 0; nt < 4; ++nt)
        acc[mt][nt] = __builtin_amdgcn_mfma_f32_16x16x32_bf16(af[mt], bf[nt], acc[mt][nt], 0, 0, 0);
  };

  // prologue: tiles 0..3 in flight, tile 0 staged
  issueB(0, 0); issueB(1, 1); issueB(2, 2); issueB(3, 3);
  loadA(0, af0);
  writeB(0, 0);
  BAR();

  #pragma unroll 1
  for (int k = 0; k < NSTEP; k += 4){
    // s=k : consume Bs[0]/af0 (tile k)
    loadA(k + 1, af1);
    if (k + 4 < NSTEP) issueB(k + 4, 0);
    mfmaStep(0, af0);
    writeB(1, 1);                       // tile k+1 -> Bs[1]
    BAR();
    // s=k+1 : consume Bs[1]/af1
    loadA(k + 2, af0);
    if (k + 5 < NSTEP) issueB(k + 5, 1);
    mfmaStep(1, af1);
    writeB(2, 0);                       // tile k+2 -> Bs[0]
    BAR();
    // s=k+2 : consume Bs[0]/af0
    loadA(k + 3, af1);
    if (k + 6 < NSTEP) issueB(k + 6, 2);
    mfmaStep(0, af0);
    writeB(3, 1);                       // tile k+3 -> Bs[1]
    BAR();
    // s=k+3 : consume Bs[1]/af1
    if (k + 4 < NSTEP) loadA(k + 4, af0);
    if (k + 7 < NSTEP) issueB(k + 7, 3);
    mfmaStep(1, af1);
    if (k + 4 < NSTEP) writeB(0, 0);    // tile k+4 -> Bs[0]
    BAR();
  }

  // fused LSTM epilogue; dw2-region blocks (128..255) also reduce z-partials
  const bool isDw2 = (j0 >= 2048) && (j0 < 4096);
  const int  rIdx  = (j0 - 2048) >> 9;
  const int  i0    = (j0 - 2048) & 511;

  #pragma unroll
  for (int mt = 0; mt < 4; ++mt){
    #pragma unroll
    for (int r2 = 0; r2 < 4; ++r2){
      const int brow = wrow + mt * 16 + q * 4 + r2;
      float iv = acc[mt][0][r2];
      float fv = acc[mt][1][r2];
      float gv = acc[mt][2][r2];
      float ov = acc[mt][3][r2];
      float cp = c0[(long)brow * H_DIM + jj];
      float cn = sigm(fv) * cp + sigm(iv) * tanh_fast(gv);
      float hn = sigm(ov) * tanh_fast(cn);
      outH[(long)brow * H_DIM + jj] = hn;
      outC[(long)brow * H_DIM + jj] = cn;
      if (isDw2){
        // z[brow, rIdx] += sum over this block's 16 i-columns of dw2*x
        float v = hn * x[(long)brow * K_X + i0 + col];
        v += __shfl_xor(v, 1); v += __shfl_xor(v, 2);
        v += __shfl_xor(v, 4); v += __shfl_xor(v, 8);
        if (col == 0) atomicAdd(&z[brow * 4 + rIdx], v);
      }
    }
  }
}

// ---------- kernel 2: y = x @ W0^T + dw1.z + db + b0  (MFMA, N-tile 16) ----------
__global__ __launch_bounds__(256) void y_kernel(
    const unsigned short* __restrict__ Abf,
    const float* __restrict__ hnew,
    const float* __restrict__ W0, const float* __restrict__ b0,
    const float* __restrict__ z,
    float* __restrict__ y)
{
  __shared__ __align__(16) unsigned short Ws[16 * 512];  // 16 KB bf16 W0 tile, swizzled
  const int t    = threadIdx.x;
  const int w    = t >> 6;
  const int l    = t & 63;
  const int q    = l >> 4;
  const int col  = l & 15;
  const int n0   = blockIdx.x * 16;
  const int wrow = w * 64;

  // stage W0 rows n0..n0+15 (all K=512) as bf16, chunk-swizzled: c' = c ^ (r&7)
  {
    const int r  = t >> 4;
    const int kc = (t & 15) * 32;
    const float* src = W0 + (long)(n0 + r) * 512 + kc;
    #pragma unroll
    for (int j = 0; j < 4; ++j){
      float4 a = *(const float4*)(src + j * 8);
      float4 b = *(const float4*)(src + j * 8 + 4);
      uint4 wv;
      wv.x = pkbf(a.x, a.y); wv.y = pkbf(a.z, a.w);
      wv.z = pkbf(b.x, b.y); wv.w = pkbf(b.z, b.w);
      const int cch = (kc >> 3) + j;
      const int sw  = cch ^ (r & 7);
      *(uint4*)((char*)Ws + r * 1024 + sw * 16) = wv;
    }
  }
  __syncthreads();

  const long aBase = (long)(wrow + col) * K_TOT + q * 8;   // x lives in Abf cols 0..511
  floatx4 acc[4];
  #pragma unroll
  for (int mt = 0; mt < 4; ++mt) acc[mt] = (floatx4){0.f, 0.f, 0.f, 0.f};

  #pragma unroll 4
  for (int ks = 0; ks < 16; ++ks){
    const int sw = (ks * 4 + q) ^ (col & 7);
    short8 bf = *(const short8*)((char*)Ws + col * 1024 + sw * 16);
    #pragma unroll
    for (int mt = 0; mt < 4; ++mt){
      short8 af = *(const short8*)(Abf + aBase + ks * 32 + (long)mt * (16 * K_TOT));
      acc[mt] = __builtin_amdgcn_mfma_f32_16x16x32_bf16(af, bf, acc[mt], 0, 0, 0);
    }
  }

  const int   o  = n0 + col;
  const float bo = b0[o];
  #pragma unroll
  for (int mt = 0; mt < 4; ++mt){
    #pragma unroll
    for (int r2 = 0; r2 < 4; ++r2){
      const int brow = wrow + mt * 16 + q * 4 + r2;
      const float* hr = hnew + (long)brow * H_DIM;
      float4 d1 = *(const float4*)(hr + o * 4);        // dw1[b,o,0..3]
      float4 zr = *(const float4*)(z + brow * 4);      // z[b,0..3]
      float val = acc[mt][r2] + bo + hr[4096 + o]
                + d1.x * zr.x + d1.y * zr.y + d1.z * zr.z + d1.w * zr.w;
      y[(long)brow * 512 + o] = val;
    }
  }
}

extern "C" void kernel_launch(void* const* d_in, const int* in_sizes, int n_in,
                              void* d_out, int out_size, void* d_ws, size_t ws_size,
                              hipStream_t stream)
{
  (void)in_sizes; (void)n_in; (void)out_size; (void)ws_size;
  const float* x   = (const float*)d_in[0];
  const float* h0  = (const float*)d_in[1];
  const float* c0  = (const float*)d_in[2];
  const float* Wih = (const float*)d_in[3];
  const float* Whh = (const float*)d_in[4];
  const float* bih = (const float*)d_in[5];
  const float* bhh = (const float*)d_in[6];
  const float* W0  = (const float*)d_in[7];
  const float* b0  = (const float*)d_in[8];

  float* out  = (float*)d_out;
  float* y    = out;                       // 256*512
  float* outH = out + 131072;              // 256*4608
  float* outC = out + 131072 + 1179648;    // 256*4608

  unsigned short* Abf = (unsigned short*)d_ws;                       // 2.62 MB bf16 [x|h0]
  float* z = (float*)((char*)d_ws + (size_t)B_DIM * K_TOT * 2);      // 4 KB (256 x 4)

  hipLaunchKernelGGL(conv_kernel, dim3(640), dim3(256), 0, stream, x, h0, Abf, z);
  hipLaunchKernelGGL(lstm_gates_kernel, dim3(288), dim3(256), 0, stream,
                     Abf, x, c0, Wih, Whh, bih, bhh, outH, outC, z);
  hipLaunchKernelGGL(y_kernel, dim3(32), dim3(256), 0, stream, Abf, outH, W0, b0, z, y);
}